// Round 15
// baseline (18.738 us; speedup 1.0000x reference)
//
#include <hip/hip_runtime.h>
#include <cmath>

// Problem constants (match the reference)
#define HH 256
#define WW 256
#define NG 1024
#define NB 2
#define NTILE 256            // tiles per batch (32x8 px)
static constexpr float FXc = 300.0f;
static constexpr float FYc = 300.0f;
static constexpr float CXc = 128.0f;
static constexpr float CYc = 128.0f;
static constexpr float EPSc = 1e-8f;
static constexpr float LOG2E = 1.4426950408889634f;

#if defined(__has_builtin)
#if __has_builtin(__builtin_amdgcn_exp2f)
#define FAST_EXP2(x) __builtin_amdgcn_exp2f(x)
#else
#define FAST_EXP2(x) exp2f(x)
#endif
#else
#define FAST_EXP2(x) exp2f(x)
#endif

typedef __attribute__((ext_vector_type(2))) float f32x2;

// SINGLE fused kernel (R13 + reduce-scatter epilogue, clamps removed):
//   grid = 512 blocks (NB*NTILE), 512 threads (8 waves), 32x8-px tile.
//   Phase 1 (cull+stage): proven cull (wave w projects [w*128,(w+1)*128)
//     in 2 rounds; EXACT circle-rect test, rcut=7.8987*s i.e.
//     k*rcut^2=-45; ballot+prefix deterministic g-ascending compaction).
//     Pre-splatted colors: gs1[g]=(r,r,g,g), gs2[g]=(b,b). Pad np to x8
//     with sentinel (k=kx=ky=0, A=-500 -> w=0, Ex=Ey=1).
//   Phase 2 (render): thread = (quad t, h): 2x2 pixel quad, 8-way
//     gaussian split; 3 exp + 3 mul weights; 8 pk accum ops.
//     NO step clamps: kept gaussians satisfy |k|*rcut<=1.14, |k|<=0.029
//     -> |d10u|,|d01u| < 4.2; NaN/inf projections fail the cull compare.
//   Epilogue: reduce-scatter (16 values, 3 halving stages, 14 shfl vs 48);
//     keep+recv order == butterfly tree order -> bit-identical sums.
//     Lane h owns values v0=8b0+4b1+2b2(h), v0+1; 4 lanes write r,
//     4 write (g,b) with den from partner (shfl_xor 4).
//   Culled-total error bound <= 1024*2^-45 -> ~0.003 even where den~EPS.
__global__ __launch_bounds__(512) void render_kernel(
    const float* __restrict__ positions,   // [N,3]
    const float* __restrict__ colors,      // [N,3]
    const float* __restrict__ opacities,   // [N,1]
    const float* __restrict__ scales,      // [N,1]
    const float* __restrict__ qvec,        // [B,4]
    const float* __restrict__ tvec,        // [B,3]
    float* __restrict__ out)               // [B,3,H,W]
{
    __shared__ float4 gs0[NG];   // (k, kx, ky, A)
    __shared__ float4 gs1[NG];   // (r, r, g, g)  pre-splatted
    __shared__ float2 gs2[NG];   // (b, b)        pre-splatted
    __shared__ int wcnt[8];

    const int b = blockIdx.x >> 8;        // 256 blocks per batch
    int tile = blockIdx.x & 255;
    if (b) tile ^= 128;                   // decorrelate per-CU load across batches
    const int x0 = (tile & 7) << 5;       // 8 tiles of 32 px in x
    const int y0 = (tile >> 3) << 3;      // 32 tiles of 8 px in y
    const float cx = (float)x0 + 15.5f;
    const float cy = (float)y0 + 3.5f;

    // --- wave-uniform rotation setup ---
    float qw = qvec[b * 4 + 0], qx = qvec[b * 4 + 1];
    float qy = qvec[b * 4 + 2], qz = qvec[b * 4 + 3];
    float rin = rsqrtf(qw * qw + qx * qx + qy * qy + qz * qz);
    qw *= rin; qx *= rin; qy *= rin; qz *= rin;
    const float r00 = 1.0f - 2.0f * (qy * qy + qz * qz);
    const float r01 = 2.0f * (qx * qy - qz * qw);
    const float r02 = 2.0f * (qx * qz + qy * qw);
    const float r10 = 2.0f * (qx * qy + qz * qw);
    const float r11 = 1.0f - 2.0f * (qx * qx + qz * qz);
    const float r12 = 2.0f * (qy * qz - qx * qw);
    const float r20 = 2.0f * (qx * qz - qy * qw);
    const float r21 = 2.0f * (qy * qz + qx * qw);
    const float r22 = 1.0f - 2.0f * (qx * qx + qy * qy);
    const float t0 = tvec[b * 3 + 0], t1 = tvec[b * 3 + 1], t2 = tvec[b * 3 + 2];

    // --- phase 1: project + cull + deterministic compaction ---
    const int wv = threadIdx.x >> 6;      // wave id [0,8)
    const int lane = threadIdx.x & 63;

    float4 pa0, pa1, pcRG0, pcRG1;        // buffered kept params (named: rule #20)
    float2 pcB0, pcB1;
    int pos0 = -1, pos1 = -1;
    int cnt = 0;                          // wave-local running count

    #pragma unroll
    for (int r = 0; r < 2; ++r) {
        const int g = wv * 128 + r * 64 + lane;
        const float X = positions[g * 3 + 0];
        const float Y = positions[g * 3 + 1];
        const float Z = positions[g * 3 + 2];
        const float cxp = r00 * X + r01 * Y + r02 * Z + t0;
        const float cyp = r10 * X + r11 * Y + r12 * Z + t1;
        const float czp = r20 * X + r21 * Y + r22 * Z + t2;
        const float iz = 1.0f / czp;
        const float ux = cxp * iz * FXc + CXc;
        const float uy = cyp * iz * FYc + CYc;
        const float s = scales[g];
        const float rcut = 7.8987f * s;
        const float ddx = fmaxf(fabsf(ux - cx) - 15.5f, 0.0f);
        const float ddy = fmaxf(fabsf(uy - cy) - 3.5f, 0.0f);
        const bool in = fmaf(ddx, ddx, ddy * ddy) <= rcut * rcut;
        const unsigned long long m = __ballot(in);
        if (in) {
            const float k = -0.5f * LOG2E / (s * s);
            const float lop = __log2f(opacities[g]);
            const float kx = -2.0f * k * ux;
            const float ky = -2.0f * k * uy;
            const float A = fmaf(k, fmaf(ux, ux, uy * uy), lop);
            const float cr = colors[g * 3 + 0];
            const float cg = colors[g * 3 + 1];
            const float cb = colors[g * 3 + 2];
            const int pre = cnt + __popcll(m & ((1ull << lane) - 1ull));
            if (r == 0) {
                pa0 = make_float4(k, kx, ky, A);
                pcRG0 = make_float4(cr, cr, cg, cg);
                pcB0 = make_float2(cb, cb);
                pos0 = pre;
            } else {
                pa1 = make_float4(k, kx, ky, A);
                pcRG1 = make_float4(cr, cr, cg, cg);
                pcB1 = make_float2(cb, cb);
                pos1 = pre;
            }
        }
        cnt += __popcll(m);
    }
    if (lane == 0) wcnt[wv] = cnt;
    __syncthreads();

    int base = 0, npTot = 0;
    #pragma unroll
    for (int j = 0; j < 8; ++j) {
        const int c = wcnt[j];
        if (j < wv) base += c;
        npTot += c;
    }
    if (pos0 >= 0) {
        gs0[base + pos0] = pa0; gs1[base + pos0] = pcRG0; gs2[base + pos0] = pcB0;
    }
    if (pos1 >= 0) {
        gs0[base + pos1] = pa1; gs1[base + pos1] = pcRG1; gs2[base + pos1] = pcB1;
    }
    const int np = (npTot + 7) & ~7;      // pad to multiple of 8
    if ((int)threadIdx.x < np - npTot) {  // sentinel: w=0, Ex=Ey=1
        gs0[npTot + threadIdx.x] = make_float4(0.0f, 0.0f, 0.0f, -500.0f);
        gs1[npTot + threadIdx.x] = make_float4(0.0f, 0.0f, 0.0f, 0.0f);
        gs2[npTot + threadIdx.x] = make_float2(0.0f, 0.0f);
    }
    __syncthreads();

    // --- phase 2: render ---
    const int h = threadIdx.x & 7;        // gaussian split lane
    const int t = threadIdx.x >> 3;       // quad id [0,64)
    const int px0i = x0 + ((t & 15) << 1);
    const int py0i = y0 + ((t >> 4) << 1);
    const float px = (float)px0i;
    const float py = (float)py0i;
    const float c2 = fmaf(px, px, py * py);
    const float u = fmaf(2.0f, px, 1.0f);
    const float v = fmaf(2.0f, py, 1.0f);

    // packed accumulators: A=(p00,p10), B=(p01,p11)
    f32x2 adenA = {0.f, 0.f}, adenB = {0.f, 0.f};
    f32x2 arA = adenA, arB = adenA;
    f32x2 agA = adenA, agB = adenA;
    f32x2 abA = adenA, abB = adenA;

    const int iters = np >> 3;
    #pragma unroll 4
    for (int i = 0; i < iters; ++i) {
        const int g = (i << 3) + h;
        const float4 g0 = gs0[g];
        const float4 cRG = gs1[g];        // (r,r,g,g): two aligned pk pairs
        const float2 cBB = gs2[g];        // (b,b): one aligned pk pair
        const float k = g0.x;
        float e00 = fmaf(k, c2, g0.w);
        e00 = fmaf(g0.y, px, e00);
        e00 = fmaf(g0.z, py, e00);
        const float d10 = fmaf(k, u, g0.y);   // |.| < 4.2, no clamp needed
        const float d01 = fmaf(k, v, g0.z);
        const float w00 = FAST_EXP2(e00);
        const float Ex = FAST_EXP2(d10);
        const float Ey = FAST_EXP2(d01);
        const float w10 = w00 * Ex;
        const float w01 = w00 * Ey;
        const float w11 = w10 * Ey;
        f32x2 WA; WA.x = w00; WA.y = w10;
        f32x2 WB; WB.x = w01; WB.y = w11;
        f32x2 rr; rr.x = cRG.x; rr.y = cRG.y;
        f32x2 gg; gg.x = cRG.z; gg.y = cRG.w;
        f32x2 bb; bb.x = cBB.x; bb.y = cBB.y;
        adenA += WA;                      // v_pk_add_f32
        adenB += WB;
        arA = __builtin_elementwise_fma(WA, rr, arA);  // v_pk_fma_f32
        arB = __builtin_elementwise_fma(WB, rr, arB);
        agA = __builtin_elementwise_fma(WA, gg, agA);
        agB = __builtin_elementwise_fma(WB, gg, agB);
        abA = __builtin_elementwise_fma(WA, bb, abA);
        abB = __builtin_elementwise_fma(WB, bb, abB);
    }

    // --- reduce-scatter over the 8-lane split group (14 shfl, not 48) ---
    // Value order acc[p*4+ch], p = x + 2y in the quad, ch: 0=den,1=r,2=g,3=b
    float acc[16];
    acc[0] = adenA.x; acc[1] = arA.x; acc[2]  = agA.x; acc[3]  = abA.x;  // (0,0)
    acc[4] = adenA.y; acc[5] = arA.y; acc[6]  = agA.y; acc[7]  = abA.y;  // (1,0)
    acc[8] = adenB.x; acc[9] = arB.x; acc[10] = agB.x; acc[11] = abB.x;  // (0,1)
    acc[12] = adenB.y; acc[13] = arB.y; acc[14] = agB.y; acc[15] = abB.y;// (1,1)

    {   // stage 1: m=1, 16 -> 8
        const bool hi = (h & 1) != 0;
        #pragma unroll
        for (int j = 0; j < 8; ++j) {
            const float send = hi ? acc[j] : acc[j + 8];
            const float keep = hi ? acc[j + 8] : acc[j];
            acc[j] = keep + __shfl_xor(send, 1);
        }
    }
    {   // stage 2: m=2, 8 -> 4
        const bool hi = (h & 2) != 0;
        #pragma unroll
        for (int j = 0; j < 4; ++j) {
            const float send = hi ? acc[j] : acc[j + 4];
            const float keep = hi ? acc[j + 4] : acc[j];
            acc[j] = keep + __shfl_xor(send, 2);
        }
    }
    {   // stage 3: m=4, 4 -> 2
        const bool hi = (h & 4) != 0;
        #pragma unroll
        for (int j = 0; j < 2; ++j) {
            const float send = hi ? acc[j] : acc[j + 2];
            const float keep = hi ? acc[j + 2] : acc[j];
            acc[j] = keep + __shfl_xor(send, 4);
        }
    }

    // lane h owns values v0 = 8*b0 + 4*b1 + 2*b2, v0+1
    const int v0 = ((h & 1) << 3) | ((h & 2) << 1) | ((h & 4) >> 1);
    const int p = v0 >> 2;                // pixel 0..3 (x + 2y)
    const bool gb = (v0 & 2) != 0;        // holds (g,b)? else (den,r)
    const float denOther = __shfl_xor(acc[0], 4);  // partner flips b2
    const float den = gb ? denOther : acc[0];
    const float inv = 1.0f / (den + EPSc);
    const int pxx = px0i + (p & 1);
    const int pyy = py0i + (p >> 1);
    const size_t o = (size_t)b * 3 * 65536 + (size_t)pyy * WW + pxx;
    if (gb) {
        out[o + 65536]  = acc[0] * inv;   // g
        out[o + 131072] = acc[1] * inv;   // b
    } else {
        out[o] = acc[1] * inv;            // r
    }
}

extern "C" void kernel_launch(void* const* d_in, const int* in_sizes, int n_in,
                              void* d_out, int out_size, void* d_ws, size_t ws_size,
                              hipStream_t stream) {
    const float* positions = (const float*)d_in[0];
    const float* colors    = (const float*)d_in[1];
    const float* opacities = (const float*)d_in[2];
    const float* scales    = (const float*)d_in[3];
    const float* qvec      = (const float*)d_in[4];
    const float* tvec      = (const float*)d_in[5];
    float* out = (float*)d_out;

    render_kernel<<<dim3(NB * NTILE), dim3(512), 0, stream>>>(
        positions, colors, opacities, scales, qvec, tvec, out);
}

// Round 16
// 12.859 us; speedup vs baseline: 1.4571x; 1.4571x over previous
//
#include <hip/hip_runtime.h>
#include <cmath>

// Problem constants (match the reference)
#define HH 256
#define WW 256
#define NG 1024
#define NB 2
#define NTILE 256            // tiles per batch (32x8 px)
static constexpr float FXc = 300.0f;
static constexpr float FYc = 300.0f;
static constexpr float CXc = 128.0f;
static constexpr float CYc = 128.0f;
static constexpr float EPSc = 1e-8f;
static constexpr float LOG2E = 1.4426950408889634f;

#if defined(__has_builtin)
#if __has_builtin(__builtin_amdgcn_exp2f)
#define FAST_EXP2(x) __builtin_amdgcn_exp2f(x)
#else
#define FAST_EXP2(x) exp2f(x)
#endif
#else
#define FAST_EXP2(x) exp2f(x)
#endif

typedef __attribute__((ext_vector_type(2))) float f32x2;

// SINGLE fused kernel (R13 structure + dead-clamp removal):
//   grid = 512 blocks (NB*NTILE), 512 threads (8 waves), 32x8-px tile.
//   Phase 1 (cull+stage): wave w projects gaussians [w*128,(w+1)*128) in
//     2 rounds of 64; EXACT circle-rect test (rcut = 7.8987*s, i.e.
//     k*rcut^2 = -45); ballot + intra-wave prefix gives deterministic
//     g-ascending compaction into LDS (no atomics). Padded to x8 with a
//     sentinel (k=kx=ky=0, A=-500 -> w=0, Ex=Ey=1).
//   LDS color layout PRE-SPLATTED so v_pk_fma operands need no movs:
//     gs1[g] = (r,r,g,g), gs2[g] = (b,b); all reads share one addr reg.
//   Phase 2 (render): thread = (quad t, h): 2x2 pixel quad, 8-way
//     gaussian split; 3 exp + 3 mul weights; 8 pk accum ops
//     (A-half=(p00,p10), B-half=(p01,p11)); 3-stage butterfly; lanes
//     h<4 write the quad's pixels.
//   NO step clamps (dead code under the circle cull): kept gaussians have
//     |k|*rcut <= 1.14, |k| <= 0.029 -> |d10|,|d01| < 4.4 << 126; NaN/inf
//     projections fail the cull compare and never reach LDS.
//   Culled-total error bound <= 1024*2^-45 -> ~0.003 even where den~EPS.
__global__ __launch_bounds__(512) void render_kernel(
    const float* __restrict__ positions,   // [N,3]
    const float* __restrict__ colors,      // [N,3]
    const float* __restrict__ opacities,   // [N,1]
    const float* __restrict__ scales,      // [N,1]
    const float* __restrict__ qvec,        // [B,4]
    const float* __restrict__ tvec,        // [B,3]
    float* __restrict__ out)               // [B,3,H,W]
{
    __shared__ float4 gs0[NG];   // (k, kx, ky, A)
    __shared__ float4 gs1[NG];   // (r, r, g, g)  pre-splatted
    __shared__ float2 gs2[NG];   // (b, b)        pre-splatted
    __shared__ int wcnt[8];

    const int b = blockIdx.x >> 8;        // 256 blocks per batch
    int tile = blockIdx.x & 255;
    if (b) tile ^= 128;                   // decorrelate per-CU load across batches
    const int x0 = (tile & 7) << 5;       // 8 tiles of 32 px in x
    const int y0 = (tile >> 3) << 3;      // 32 tiles of 8 px in y
    const float cx = (float)x0 + 15.5f;
    const float cy = (float)y0 + 3.5f;

    // --- wave-uniform rotation setup ---
    float qw = qvec[b * 4 + 0], qx = qvec[b * 4 + 1];
    float qy = qvec[b * 4 + 2], qz = qvec[b * 4 + 3];
    float rin = rsqrtf(qw * qw + qx * qx + qy * qy + qz * qz);
    qw *= rin; qx *= rin; qy *= rin; qz *= rin;
    const float r00 = 1.0f - 2.0f * (qy * qy + qz * qz);
    const float r01 = 2.0f * (qx * qy - qz * qw);
    const float r02 = 2.0f * (qx * qz + qy * qw);
    const float r10 = 2.0f * (qx * qy + qz * qw);
    const float r11 = 1.0f - 2.0f * (qx * qx + qz * qz);
    const float r12 = 2.0f * (qy * qz - qx * qw);
    const float r20 = 2.0f * (qx * qz - qy * qw);
    const float r21 = 2.0f * (qy * qz + qx * qw);
    const float r22 = 1.0f - 2.0f * (qx * qx + qy * qy);
    const float t0 = tvec[b * 3 + 0], t1 = tvec[b * 3 + 1], t2 = tvec[b * 3 + 2];

    // --- phase 1: project + cull + deterministic compaction ---
    const int wv = threadIdx.x >> 6;      // wave id [0,8)
    const int lane = threadIdx.x & 63;

    float4 pa0, pa1, pcRG0, pcRG1;        // buffered kept params (named: rule #20)
    float2 pcB0, pcB1;
    int pos0 = -1, pos1 = -1;
    int cnt = 0;                          // wave-local running count

    #pragma unroll
    for (int r = 0; r < 2; ++r) {
        const int g = wv * 128 + r * 64 + lane;
        const float X = positions[g * 3 + 0];
        const float Y = positions[g * 3 + 1];
        const float Z = positions[g * 3 + 2];
        const float cxp = r00 * X + r01 * Y + r02 * Z + t0;
        const float cyp = r10 * X + r11 * Y + r12 * Z + t1;
        const float czp = r20 * X + r21 * Y + r22 * Z + t2;
        const float iz = 1.0f / czp;
        const float ux = cxp * iz * FXc + CXc;
        const float uy = cyp * iz * FYc + CYc;
        const float s = scales[g];
        const float rcut = 7.8987f * s;
        const float ddx = fmaxf(fabsf(ux - cx) - 15.5f, 0.0f);
        const float ddy = fmaxf(fabsf(uy - cy) - 3.5f, 0.0f);
        const bool in = fmaf(ddx, ddx, ddy * ddy) <= rcut * rcut;
        const unsigned long long m = __ballot(in);
        if (in) {
            const float k = -0.5f * LOG2E / (s * s);
            const float lop = __log2f(opacities[g]);
            const float kx = -2.0f * k * ux;
            const float ky = -2.0f * k * uy;
            const float A = fmaf(k, fmaf(ux, ux, uy * uy), lop);
            const float cr = colors[g * 3 + 0];
            const float cg = colors[g * 3 + 1];
            const float cb = colors[g * 3 + 2];
            const int pre = cnt + __popcll(m & ((1ull << lane) - 1ull));
            if (r == 0) {
                pa0 = make_float4(k, kx, ky, A);
                pcRG0 = make_float4(cr, cr, cg, cg);
                pcB0 = make_float2(cb, cb);
                pos0 = pre;
            } else {
                pa1 = make_float4(k, kx, ky, A);
                pcRG1 = make_float4(cr, cr, cg, cg);
                pcB1 = make_float2(cb, cb);
                pos1 = pre;
            }
        }
        cnt += __popcll(m);
    }
    if (lane == 0) wcnt[wv] = cnt;
    __syncthreads();

    int base = 0, npTot = 0;
    #pragma unroll
    for (int j = 0; j < 8; ++j) {
        const int c = wcnt[j];
        if (j < wv) base += c;
        npTot += c;
    }
    if (pos0 >= 0) {
        gs0[base + pos0] = pa0; gs1[base + pos0] = pcRG0; gs2[base + pos0] = pcB0;
    }
    if (pos1 >= 0) {
        gs0[base + pos1] = pa1; gs1[base + pos1] = pcRG1; gs2[base + pos1] = pcB1;
    }
    const int np = (npTot + 7) & ~7;      // pad to multiple of 8
    if ((int)threadIdx.x < np - npTot) {  // sentinel: w=0, Ex=Ey=1
        gs0[npTot + threadIdx.x] = make_float4(0.0f, 0.0f, 0.0f, -500.0f);
        gs1[npTot + threadIdx.x] = make_float4(0.0f, 0.0f, 0.0f, 0.0f);
        gs2[npTot + threadIdx.x] = make_float2(0.0f, 0.0f);
    }
    __syncthreads();

    // --- phase 2: render ---
    const int h = threadIdx.x & 7;        // gaussian split lane
    const int t = threadIdx.x >> 3;       // quad id [0,64)
    const int px0i = x0 + ((t & 15) << 1);
    const int py0i = y0 + ((t >> 4) << 1);
    const float px = (float)px0i;
    const float py = (float)py0i;
    const float c2 = fmaf(px, px, py * py);
    const float u = fmaf(2.0f, px, 1.0f);
    const float v = fmaf(2.0f, py, 1.0f);

    // packed accumulators: A=(p00,p10), B=(p01,p11)
    f32x2 adenA = {0.f, 0.f}, adenB = {0.f, 0.f};
    f32x2 arA = adenA, arB = adenA;
    f32x2 agA = adenA, agB = adenA;
    f32x2 abA = adenA, abB = adenA;

    const int iters = np >> 3;
    #pragma unroll 4
    for (int i = 0; i < iters; ++i) {
        const int g = (i << 3) + h;
        const float4 g0 = gs0[g];
        const float4 cRG = gs1[g];        // (r,r,g,g): two aligned pk pairs
        const float2 cBB = gs2[g];        // (b,b): one aligned pk pair
        const float k = g0.x;
        float e00 = fmaf(k, c2, g0.w);
        e00 = fmaf(g0.y, px, e00);
        e00 = fmaf(g0.z, py, e00);
        const float d10 = fmaf(k, u, g0.y);   // |.| < 4.4 (cull-bounded)
        const float d01 = fmaf(k, v, g0.z);
        const float w00 = FAST_EXP2(e00);
        const float Ex = FAST_EXP2(d10);
        const float Ey = FAST_EXP2(d01);
        const float w10 = w00 * Ex;
        const float w01 = w00 * Ey;
        const float w11 = w10 * Ey;
        f32x2 WA; WA.x = w00; WA.y = w10;
        f32x2 WB; WB.x = w01; WB.y = w11;
        f32x2 rr; rr.x = cRG.x; rr.y = cRG.y;
        f32x2 gg; gg.x = cRG.z; gg.y = cRG.w;
        f32x2 bb; bb.x = cBB.x; bb.y = cBB.y;
        adenA += WA;                      // v_pk_add_f32
        adenB += WB;
        arA = __builtin_elementwise_fma(WA, rr, arA);  // v_pk_fma_f32
        arB = __builtin_elementwise_fma(WB, rr, arB);
        agA = __builtin_elementwise_fma(WA, gg, agA);
        agB = __builtin_elementwise_fma(WB, gg, agB);
        abA = __builtin_elementwise_fma(WA, bb, abA);
        abB = __builtin_elementwise_fma(WB, bb, abB);
    }

    // unpack to the scalar layout: x=(0,0), y=(+1,0), z=(0,+1), w=(+1,+1)
    float4 aden = make_float4(adenA.x, adenA.y, adenB.x, adenB.y);
    float4 ar   = make_float4(arA.x,   arA.y,   arB.x,   arB.y);
    float4 ag   = make_float4(agA.x,   agA.y,   agB.x,   agB.y);
    float4 ab   = make_float4(abA.x,   abA.y,   abB.x,   abB.y);

    // --- butterfly combine across the 8-lane split group ---
    #pragma unroll
    for (int m = 1; m <= 4; m <<= 1) {
        aden.x += __shfl_xor(aden.x, m); aden.y += __shfl_xor(aden.y, m);
        aden.z += __shfl_xor(aden.z, m); aden.w += __shfl_xor(aden.w, m);
        ar.x += __shfl_xor(ar.x, m); ar.y += __shfl_xor(ar.y, m);
        ar.z += __shfl_xor(ar.z, m); ar.w += __shfl_xor(ar.w, m);
        ag.x += __shfl_xor(ag.x, m); ag.y += __shfl_xor(ag.y, m);
        ag.z += __shfl_xor(ag.z, m); ag.w += __shfl_xor(ag.w, m);
        ab.x += __shfl_xor(ab.x, m); ab.y += __shfl_xor(ab.y, m);
        ab.z += __shfl_xor(ab.z, m); ab.w += __shfl_xor(ab.w, m);
    }

    // --- epilogue: lanes h<4 each write one pixel of the quad ---
    if (h < 4) {
        float den, cr, cg, cb;
        if (h == 0)      { den = aden.x; cr = ar.x; cg = ag.x; cb = ab.x; }
        else if (h == 1) { den = aden.y; cr = ar.y; cg = ag.y; cb = ab.y; }
        else if (h == 2) { den = aden.z; cr = ar.z; cg = ag.z; cb = ab.z; }
        else             { den = aden.w; cr = ar.w; cg = ag.w; cb = ab.w; }
        const int pxx = px0i + (h & 1);
        const int pyy = py0i + (h >> 1);
        const float inv = 1.0f / (den + EPSc);
        const size_t o = (size_t)b * 3 * 65536 + (size_t)pyy * WW + pxx;
        out[o]           = cr * inv;
        out[o + 65536]   = cg * inv;
        out[o + 131072]  = cb * inv;
    }
}

extern "C" void kernel_launch(void* const* d_in, const int* in_sizes, int n_in,
                              void* d_out, int out_size, void* d_ws, size_t ws_size,
                              hipStream_t stream) {
    const float* positions = (const float*)d_in[0];
    const float* colors    = (const float*)d_in[1];
    const float* opacities = (const float*)d_in[2];
    const float* scales    = (const float*)d_in[3];
    const float* qvec      = (const float*)d_in[4];
    const float* tvec      = (const float*)d_in[5];
    float* out = (float*)d_out;

    render_kernel<<<dim3(NB * NTILE), dim3(512), 0, stream>>>(
        positions, colors, opacities, scales, qvec, tvec, out);
}

// Round 17
// 11.788 us; speedup vs baseline: 1.5896x; 1.0909x over previous
//
#include <hip/hip_runtime.h>
#include <cmath>

// Problem constants (match the reference)
#define HH 256
#define WW 256
#define NG 1024
#define NB 2
#define NTILE 256            // tiles per batch (32x8 px)
static constexpr float FXc = 300.0f;
static constexpr float FYc = 300.0f;
static constexpr float CXc = 128.0f;
static constexpr float CYc = 128.0f;
static constexpr float EPSc = 1e-8f;
static constexpr float LOG2E = 1.4426950408889634f;

#if defined(__has_builtin)
#if __has_builtin(__builtin_amdgcn_exp2f)
#define FAST_EXP2(x) __builtin_amdgcn_exp2f(x)
#else
#define FAST_EXP2(x) exp2f(x)
#endif
#else
#define FAST_EXP2(x) exp2f(x)
#endif

typedef __attribute__((ext_vector_type(2))) float f32x2;

// FINAL kernel == R13 (best measured: 11.92 us), restored byte-for-byte
// after R16's clamp-removal measured as a noise/scheduling regression.
//   grid = 512 blocks (NB*NTILE), 512 threads (8 waves), 32x8-px tile.
//   Phase 1 (cull+stage): wave w projects gaussians [w*128,(w+1)*128) in
//     2 rounds of 64; exact circle-rect test (rcut = 7.8987*s, i.e.
//     k*rcut^2 = -45); ballot + intra-wave prefix gives deterministic
//     g-ascending compaction into LDS (no atomics). Padded to x8 with a
//     sentinel (k=kx=ky=0, A=-500 -> w=0, Ex=Ey=1).
//   LDS color layout PRE-SPLATTED so v_pk_fma operands need no movs:
//     gs1[g] = (r,r,g,g), gs2[g] = (b,b); all reads share one addr reg.
//   Phase 2 (render): thread = (quad t, h): 2x2 pixel quad, 8-way
//     gaussian split; 3 exp + 3 mul weights (step deltas clamped <=126;
//     belt-and-suspenders vs 0*inf); 8 pk accum ops (A=(p00,p10),
//     B=(p01,p11)); 3-stage butterfly; lanes h<4 write the quad.
//   Culled-total error bound <= 1024*2^-45 -> ~0.003 even where den~EPS.
__global__ __launch_bounds__(512) void render_kernel(
    const float* __restrict__ positions,   // [N,3]
    const float* __restrict__ colors,      // [N,3]
    const float* __restrict__ opacities,   // [N,1]
    const float* __restrict__ scales,      // [N,1]
    const float* __restrict__ qvec,        // [B,4]
    const float* __restrict__ tvec,        // [B,3]
    float* __restrict__ out)               // [B,3,H,W]
{
    __shared__ float4 gs0[NG];   // (k, kx, ky, A)
    __shared__ float4 gs1[NG];   // (r, r, g, g)  pre-splatted
    __shared__ float2 gs2[NG];   // (b, b)        pre-splatted
    __shared__ int wcnt[8];

    const int b = blockIdx.x >> 8;        // 256 blocks per batch
    int tile = blockIdx.x & 255;
    if (b) tile ^= 128;                   // decorrelate per-CU load across batches
    const int x0 = (tile & 7) << 5;       // 8 tiles of 32 px in x
    const int y0 = (tile >> 3) << 3;      // 32 tiles of 8 px in y
    const float cx = (float)x0 + 15.5f;
    const float cy = (float)y0 + 3.5f;

    // --- wave-uniform rotation setup ---
    float qw = qvec[b * 4 + 0], qx = qvec[b * 4 + 1];
    float qy = qvec[b * 4 + 2], qz = qvec[b * 4 + 3];
    float rin = rsqrtf(qw * qw + qx * qx + qy * qy + qz * qz);
    qw *= rin; qx *= rin; qy *= rin; qz *= rin;
    const float r00 = 1.0f - 2.0f * (qy * qy + qz * qz);
    const float r01 = 2.0f * (qx * qy - qz * qw);
    const float r02 = 2.0f * (qx * qz + qy * qw);
    const float r10 = 2.0f * (qx * qy + qz * qw);
    const float r11 = 1.0f - 2.0f * (qx * qx + qz * qz);
    const float r12 = 2.0f * (qy * qz - qx * qw);
    const float r20 = 2.0f * (qx * qz - qy * qw);
    const float r21 = 2.0f * (qy * qz + qx * qw);
    const float r22 = 1.0f - 2.0f * (qx * qx + qy * qy);
    const float t0 = tvec[b * 3 + 0], t1 = tvec[b * 3 + 1], t2 = tvec[b * 3 + 2];

    // --- phase 1: project + cull + deterministic compaction ---
    const int wv = threadIdx.x >> 6;      // wave id [0,8)
    const int lane = threadIdx.x & 63;

    float4 pa0, pa1, pcRG0, pcRG1;        // buffered kept params (named: rule #20)
    float2 pcB0, pcB1;
    int pos0 = -1, pos1 = -1;
    int cnt = 0;                          // wave-local running count

    #pragma unroll
    for (int r = 0; r < 2; ++r) {
        const int g = wv * 128 + r * 64 + lane;
        const float X = positions[g * 3 + 0];
        const float Y = positions[g * 3 + 1];
        const float Z = positions[g * 3 + 2];
        const float cxp = r00 * X + r01 * Y + r02 * Z + t0;
        const float cyp = r10 * X + r11 * Y + r12 * Z + t1;
        const float czp = r20 * X + r21 * Y + r22 * Z + t2;
        const float iz = 1.0f / czp;
        const float ux = cxp * iz * FXc + CXc;
        const float uy = cyp * iz * FYc + CYc;
        const float s = scales[g];
        const float rcut = 7.8987f * s;
        const float ddx = fmaxf(fabsf(ux - cx) - 15.5f, 0.0f);
        const float ddy = fmaxf(fabsf(uy - cy) - 3.5f, 0.0f);
        const bool in = fmaf(ddx, ddx, ddy * ddy) <= rcut * rcut;
        const unsigned long long m = __ballot(in);
        if (in) {
            const float k = -0.5f * LOG2E / (s * s);
            const float lop = __log2f(opacities[g]);
            const float kx = -2.0f * k * ux;
            const float ky = -2.0f * k * uy;
            const float A = fmaf(k, fmaf(ux, ux, uy * uy), lop);
            const float cr = colors[g * 3 + 0];
            const float cg = colors[g * 3 + 1];
            const float cb = colors[g * 3 + 2];
            const int pre = cnt + __popcll(m & ((1ull << lane) - 1ull));
            if (r == 0) {
                pa0 = make_float4(k, kx, ky, A);
                pcRG0 = make_float4(cr, cr, cg, cg);
                pcB0 = make_float2(cb, cb);
                pos0 = pre;
            } else {
                pa1 = make_float4(k, kx, ky, A);
                pcRG1 = make_float4(cr, cr, cg, cg);
                pcB1 = make_float2(cb, cb);
                pos1 = pre;
            }
        }
        cnt += __popcll(m);
    }
    if (lane == 0) wcnt[wv] = cnt;
    __syncthreads();

    int base = 0, npTot = 0;
    #pragma unroll
    for (int j = 0; j < 8; ++j) {
        const int c = wcnt[j];
        if (j < wv) base += c;
        npTot += c;
    }
    if (pos0 >= 0) {
        gs0[base + pos0] = pa0; gs1[base + pos0] = pcRG0; gs2[base + pos0] = pcB0;
    }
    if (pos1 >= 0) {
        gs0[base + pos1] = pa1; gs1[base + pos1] = pcRG1; gs2[base + pos1] = pcB1;
    }
    const int np = (npTot + 7) & ~7;      // pad to multiple of 8
    if ((int)threadIdx.x < np - npTot) {  // sentinel: w=0, Ex=Ey=1
        gs0[npTot + threadIdx.x] = make_float4(0.0f, 0.0f, 0.0f, -500.0f);
        gs1[npTot + threadIdx.x] = make_float4(0.0f, 0.0f, 0.0f, 0.0f);
        gs2[npTot + threadIdx.x] = make_float2(0.0f, 0.0f);
    }
    __syncthreads();

    // --- phase 2: render ---
    const int h = threadIdx.x & 7;        // gaussian split lane
    const int t = threadIdx.x >> 3;       // quad id [0,64)
    const int px0i = x0 + ((t & 15) << 1);
    const int py0i = y0 + ((t >> 4) << 1);
    const float px = (float)px0i;
    const float py = (float)py0i;
    const float c2 = fmaf(px, px, py * py);
    const float u = fmaf(2.0f, px, 1.0f);
    const float v = fmaf(2.0f, py, 1.0f);

    // packed accumulators: A=(p00,p10), B=(p01,p11)
    f32x2 adenA = {0.f, 0.f}, adenB = {0.f, 0.f};
    f32x2 arA = adenA, arB = adenA;
    f32x2 agA = adenA, agB = adenA;
    f32x2 abA = adenA, abB = adenA;

    const int iters = np >> 3;
    #pragma unroll 4
    for (int i = 0; i < iters; ++i) {
        const int g = (i << 3) + h;
        const float4 g0 = gs0[g];
        const float4 cRG = gs1[g];        // (r,r,g,g): two aligned pk pairs
        const float2 cBB = gs2[g];        // (b,b): one aligned pk pair
        const float k = g0.x;
        float e00 = fmaf(k, c2, g0.w);
        e00 = fmaf(g0.y, px, e00);
        e00 = fmaf(g0.z, py, e00);
        const float d10 = fminf(fmaf(k, u, g0.y), 126.0f);
        const float d01 = fminf(fmaf(k, v, g0.z), 126.0f);
        const float w00 = FAST_EXP2(e00);
        const float Ex = FAST_EXP2(d10);
        const float Ey = FAST_EXP2(d01);
        const float w10 = w00 * Ex;
        const float w01 = w00 * Ey;
        const float w11 = w10 * Ey;
        f32x2 WA; WA.x = w00; WA.y = w10;
        f32x2 WB; WB.x = w01; WB.y = w11;
        f32x2 rr; rr.x = cRG.x; rr.y = cRG.y;
        f32x2 gg; gg.x = cRG.z; gg.y = cRG.w;
        f32x2 bb; bb.x = cBB.x; bb.y = cBB.y;
        adenA += WA;                      // v_pk_add_f32
        adenB += WB;
        arA = __builtin_elementwise_fma(WA, rr, arA);  // v_pk_fma_f32
        arB = __builtin_elementwise_fma(WB, rr, arB);
        agA = __builtin_elementwise_fma(WA, gg, agA);
        agB = __builtin_elementwise_fma(WB, gg, agB);
        abA = __builtin_elementwise_fma(WA, bb, abA);
        abB = __builtin_elementwise_fma(WB, bb, abB);
    }

    // unpack to the scalar layout: x=(0,0), y=(+1,0), z=(0,+1), w=(+1,+1)
    float4 aden = make_float4(adenA.x, adenA.y, adenB.x, adenB.y);
    float4 ar   = make_float4(arA.x,   arA.y,   arB.x,   arB.y);
    float4 ag   = make_float4(agA.x,   agA.y,   agB.x,   agB.y);
    float4 ab   = make_float4(abA.x,   abA.y,   abB.x,   abB.y);

    // --- butterfly combine across the 8-lane split group ---
    #pragma unroll
    for (int m = 1; m <= 4; m <<= 1) {
        aden.x += __shfl_xor(aden.x, m); aden.y += __shfl_xor(aden.y, m);
        aden.z += __shfl_xor(aden.z, m); aden.w += __shfl_xor(aden.w, m);
        ar.x += __shfl_xor(ar.x, m); ar.y += __shfl_xor(ar.y, m);
        ar.z += __shfl_xor(ar.z, m); ar.w += __shfl_xor(ar.w, m);
        ag.x += __shfl_xor(ag.x, m); ag.y += __shfl_xor(ag.y, m);
        ag.z += __shfl_xor(ag.z, m); ag.w += __shfl_xor(ag.w, m);
        ab.x += __shfl_xor(ab.x, m); ab.y += __shfl_xor(ab.y, m);
        ab.z += __shfl_xor(ab.z, m); ab.w += __shfl_xor(ab.w, m);
    }

    // --- epilogue: lanes h<4 each write one pixel of the quad ---
    if (h < 4) {
        float den, cr, cg, cb;
        if (h == 0)      { den = aden.x; cr = ar.x; cg = ag.x; cb = ab.x; }
        else if (h == 1) { den = aden.y; cr = ar.y; cg = ag.y; cb = ab.y; }
        else if (h == 2) { den = aden.z; cr = ar.z; cg = ag.z; cb = ab.z; }
        else             { den = aden.w; cr = ar.w; cg = ag.w; cb = ab.w; }
        const int pxx = px0i + (h & 1);
        const int pyy = py0i + (h >> 1);
        const float inv = 1.0f / (den + EPSc);
        const size_t o = (size_t)b * 3 * 65536 + (size_t)pyy * WW + pxx;
        out[o]           = cr * inv;
        out[o + 65536]   = cg * inv;
        out[o + 131072]  = cb * inv;
    }
}

extern "C" void kernel_launch(void* const* d_in, const int* in_sizes, int n_in,
                              void* d_out, int out_size, void* d_ws, size_t ws_size,
                              hipStream_t stream) {
    const float* positions = (const float*)d_in[0];
    const float* colors    = (const float*)d_in[1];
    const float* opacities = (const float*)d_in[2];
    const float* scales    = (const float*)d_in[3];
    const float* qvec      = (const float*)d_in[4];
    const float* tvec      = (const float*)d_in[5];
    float* out = (float*)d_out;

    render_kernel<<<dim3(NB * NTILE), dim3(512), 0, stream>>>(
        positions, colors, opacities, scales, qvec, tvec, out);
}